// Round 2
// baseline (11069.897 us; speedup 1.0000x reference)
//
#include <hip/hip_runtime.h>
#include <hip/hip_bf16.h>

#define F_IN  256
#define UNITS 512
#define T_SEQ 1024
#define B_SZ  32
#define NCLS  50
#define NG    16   // workgroups per direction
#define SCOPE __HIP_MEMORY_SCOPE_AGENT

typedef short s16x8 __attribute__((ext_vector_type(8)));
typedef float f32x16 __attribute__((ext_vector_type(16)));

__device__ __forceinline__ ushort f2bf(float f) {
  union { float f; unsigned u; } v; v.f = f;
  unsigned r = v.u + 0x7fffu + ((v.u >> 16) & 1u);   // round-to-nearest-even
  return (ushort)(r >> 16);
}

// ---------------- prep kernels ----------------

// x [32][1024][256] f32  ->  xT [1024][32][256] bf16
__global__ void prep_xT(const float* __restrict__ x, ushort* __restrict__ xT) {
  int idx = blockIdx.x * 256 + threadIdx.x;      // chunk of 8 over [32][1024][32]
  int b = idx >> 15;
  int r = idx & 32767;
  int t = r >> 5;
  int c = r & 31;
  const float4* s4 = (const float4*)(x + ((size_t)b * T_SEQ + t) * F_IN + c * 8);
  float4 f0 = s4[0], f1 = s4[1];
  s16x8 o;
  o[0] = (short)f2bf(f0.x); o[1] = (short)f2bf(f0.y);
  o[2] = (short)f2bf(f0.z); o[3] = (short)f2bf(f0.w);
  o[4] = (short)f2bf(f1.x); o[5] = (short)f2bf(f1.y);
  o[6] = (short)f2bf(f1.z); o[7] = (short)f2bf(f1.w);
  *(s16x8*)(xT + ((size_t)t * B_SZ + b) * F_IN + c * 8) = o;
}

// UWT[d][n][k] bf16, n in [0,1536), k in [0,768): k<512 -> U_d[k][n], k>=512 -> W_d[k-512][n]
__global__ void prep_UWT(const float* __restrict__ Uf, const float* __restrict__ Wf,
                         const float* __restrict__ Ub, const float* __restrict__ Wb,
                         ushort* __restrict__ UWT) {
  int idx = blockIdx.x * 256 + threadIdx.x;      // chunk of 8 over [2][1536][96]
  int d = idx / 147456;
  int r = idx % 147456;
  int n = r / 96;
  int ck = r % 96;
  const float* U = d ? Ub : Uf;
  const float* W = d ? Wb : Wf;
  s16x8 o;
  #pragma unroll
  for (int i = 0; i < 8; ++i) {
    int k = ck * 8 + i;
    float v = (k < UNITS) ? U[(size_t)k * 1536 + n] : W[(size_t)(k - UNITS) * 1536 + n];
    o[i] = (short)f2bf(v);
  }
  *(s16x8*)(UWT + ((size_t)d * 1536 + n) * 768 + ck * 8) = o;
}

// WdT [64][1024] bf16 (rows 50..63 zero) from Wd [1024][50]
__global__ void prep_WdT(const float* __restrict__ Wd, ushort* __restrict__ WdT) {
  int idx = blockIdx.x * 256 + threadIdx.x;      // 65536
  int n = idx >> 10, k = idx & 1023;
  float v = (n < NCLS) ? Wd[(size_t)k * NCLS + n] : 0.f;
  WdT[idx] = f2bf(v);
}

// ---------------- persistent bidirectional GRU recurrence ----------------
// grid = 32 blocks (16 per direction), 192 threads (3 waves).
// All cross-WG state (h, flags) moves through RELAXED agent-scope atomics:
// sc0/sc1 write-through stores + cache-bypassing loads at the L3 coherence
// point. No acquire/release -> no buffer_wbl2 / buffer_inv per step.
__global__ __launch_bounds__(192, 1) void gru_rec(
    const ushort* __restrict__ xT,      // [1024][32][256] bf16
    const ushort* __restrict__ UWT,     // [2][1536][768] bf16
    const float* __restrict__ bias_f,   // [2][1536] f32
    const float* __restrict__ bias_b,
    ushort* __restrict__ h_out,         // [2][1024][32][512] bf16
    int* __restrict__ flags)            // [2][1024][16]
{
  const int g  = blockIdx.x;
  const int d  = g >> 4;
  const int gg = g & 15;
  const int tid  = threadIdx.x;
  const int w    = tid >> 6;
  const int lane = tid & 63;
  const int col  = lane & 31;
  const int half = lane >> 5;

  __shared__ float rec_lds[32][128];   // cols: [0,32)=z+x, [32,64)=r+x, [64,96)=rh, [96,128)=xh

  // --- B-fragment preload: 48 chunks of K=16 (192 VGPRs) ---
  s16x8 bfrag[48];
  {
    const ushort* bp = UWT + ((size_t)d * 1536 + w * UNITS + gg * 32 + col) * 768 + half * 8;
    #pragma unroll
    for (int ks = 0; ks < 48; ++ks) bfrag[ks] = *(const s16x8*)(bp + ks * 16);
  }

  // --- per-thread gate biases and persistent h state ---
  const float* bias = d ? bias_b : bias_f;
  float bz[6], br[6], bih[6], brh[6], hprev[6];
  #pragma unroll
  for (int i = 0; i < 6; ++i) {
    int e = tid + 192 * i;
    int j = gg * 32 + (e & 31);
    bz[i] = br[i] = bih[i] = brh[i] = 0.f;
    hprev[i] = 0.f;
    if (e < 1024) {
      bz[i]  = bias[j]        + bias[1536 + j];
      br[i]  = bias[512 + j]  + bias[1536 + 512 + j];
      bih[i] = bias[1024 + j];
      brh[i] = bias[1536 + 1024 + j];
    }
  }

  union U64x2 { unsigned long long q[2]; s16x8 v; };

  for (int s = 0; s < T_SEQ; ++s) {
    const int t_in = d ? (T_SEQ - 1 - s) : s;
    f32x16 acc_a, acc_b;
    #pragma unroll
    for (int i = 0; i < 16; ++i) { acc_a[i] = 0.f; acc_b[i] = 0.f; }

    // input-projection part first: independent of the flag, overlaps the spin
    {
      const ushort* xp = xT + ((size_t)t_in * B_SZ + col) * F_IN + half * 8;
      s16x8 a[16];
      #pragma unroll
      for (int i = 0; i < 16; ++i) a[i] = *(const s16x8*)(xp + i * 16);
      #pragma unroll
      for (int i = 0; i < 16; ++i)
        acc_b = __builtin_amdgcn_mfma_f32_32x32x16_bf16(a[i], bfrag[32 + i], acc_b, 0, 0, 0);
    }

    if (s > 0) {
      // spin until all 16 producer WGs of this direction published step s-1
      const int fbase = (d * T_SEQ + (s - 1)) * NG;
      const bool mine = lane < NG;
      int fv;
      do {
        fv = __hip_atomic_load(flags + fbase + (mine ? lane : 0),
                               __ATOMIC_RELAXED, SCOPE);
      } while (!__all(mine ? (fv != 0) : 1));

      const int t_prev = d ? (T_SEQ - s) : (s - 1);
      const unsigned long long* ap = (const unsigned long long*)
          (h_out + ((size_t)(d * T_SEQ + t_prev) * B_SZ + col) * UNITS + half * 8);
      // stage ALL h-fragments first so the 64 loads pipeline on one vmcnt ramp
      s16x8 areg[32];
      #pragma unroll
      for (int c = 0; c < 32; ++c) {
        U64x2 u;
        u.q[0] = __hip_atomic_load(ap + c * 4 + 0, __ATOMIC_RELAXED, SCOPE);
        u.q[1] = __hip_atomic_load(ap + c * 4 + 1, __ATOMIC_RELAXED, SCOPE);
        areg[c] = u.v;
      }
      #pragma unroll
      for (int c = 0; c < 32; ++c)
        acc_a = __builtin_amdgcn_mfma_f32_32x32x16_bf16(areg[c], bfrag[c], acc_a, 0, 0, 0);
    }

    // C/D layout (verified): col = lane&31, row = (reg&3) + 8*(reg>>2) + 4*(lane>>5)
    #pragma unroll
    for (int i = 0; i < 16; ++i) {
      int brow = (i & 3) + 8 * (i >> 2) + 4 * half;
      if (w < 2) {
        rec_lds[brow][w * 32 + col] = acc_a[i] + acc_b[i];
      } else {
        rec_lds[brow][64 + col] = acc_a[i];   // recurrent h-gate part
        rec_lds[brow][96 + col] = acc_b[i];   // input h-gate part
      }
    }
    __syncthreads();

    // gate math + publish h_new (bf16, write-through coherent stores)
    #pragma unroll
    for (int i = 0; i < 6; ++i) {
      int e = tid + 192 * i;
      if (e < 1024) {
        int b = e >> 5, j = e & 31;
        float rz = rec_lds[b][j]        + bz[i];
        float rr = rec_lds[b][32 + j]   + br[i];
        float rh = rec_lds[b][64 + j]   + brh[i];
        float xh = rec_lds[b][96 + j]   + bih[i];
        rz = fminf(fmaxf(rz, -30.f), 30.f);
        rr = fminf(fmaxf(rr, -30.f), 30.f);
        float z  = 1.f / (1.f + __expf(-rz));
        float rg = 1.f / (1.f + __expf(-rr));
        float ti = xh + rg * rh;
        ti = fminf(fmaxf(ti, -15.f), 15.f);
        float ex = __expf(2.f * ti);
        float hh = (ex - 1.f) / (ex + 1.f);
        float hn = z * hprev[i] + (1.f - z) * hh;
        hprev[i] = hn;
        __hip_atomic_store(
            h_out + ((size_t)(d * T_SEQ + t_in) * B_SZ + b) * UNITS + gg * 32 + j,
            (ushort)f2bf(hn), __ATOMIC_RELAXED, SCOPE);
      }
    }
    // __syncthreads drains vmcnt(0) in every wave -> all write-through h stores
    // have reached the coherence point before the flag RMW below.
    __syncthreads();
    if (tid == 0)
      __hip_atomic_fetch_add(flags + (d * T_SEQ + s) * NG + gg, 1,
                             __ATOMIC_RELAXED, SCOPE);
  }
}

// ---------------- dense + softmax ----------------
// grid = 256 blocks x 256 threads; wave w handles t = blockIdx*4 + w.
__global__ __launch_bounds__(256) void dense_softmax(
    const ushort* __restrict__ h_out,   // [2][1024][32][512] bf16
    const ushort* __restrict__ WdT,     // [64][1024] bf16
    const float* __restrict__ bd,       // [50]
    float* __restrict__ out)            // [32][1024][50] f32
{
  const int tid  = threadIdx.x;
  const int w    = tid >> 6, lane = tid & 63;
  const int col  = lane & 31, half = lane >> 5;
  const int t = blockIdx.x * 4 + w;

  __shared__ float lds[4][32][66];

  f32x16 acc0, acc1;
  #pragma unroll
  for (int i = 0; i < 16; ++i) { acc0[i] = 0.f; acc1[i] = 0.f; }

  const ushort* af  = h_out + ((size_t)t * B_SZ + col) * UNITS + half * 8;
  const ushort* ab  = h_out + ((size_t)(T_SEQ + t) * B_SZ + col) * UNITS + half * 8;
  const ushort* bp0 = WdT + (size_t)col * 1024 + half * 8;
  const ushort* bp1 = WdT + (size_t)(col + 32) * 1024 + half * 8;

  #pragma unroll 4
  for (int ks = 0; ks < 64; ++ks) {
    s16x8 a  = (ks < 32) ? *(const s16x8*)(af + ks * 16)
                         : *(const s16x8*)(ab + (ks - 32) * 16);
    s16x8 b0 = *(const s16x8*)(bp0 + ks * 16);
    s16x8 b1 = *(const s16x8*)(bp1 + ks * 16);
    acc0 = __builtin_amdgcn_mfma_f32_32x32x16_bf16(a, b0, acc0, 0, 0, 0);
    acc1 = __builtin_amdgcn_mfma_f32_32x32x16_bf16(a, b1, acc1, 0, 0, 0);
  }

  #pragma unroll
  for (int i = 0; i < 16; ++i) {
    int b = (i & 3) + 8 * (i >> 2) + 4 * half;
    lds[w][b][col]      = acc0[i];
    lds[w][b][32 + col] = acc1[i];
  }
  __syncthreads();

  if (tid < 128) {
    int tl = tid >> 5, b = tid & 31;
    int tt = blockIdx.x * 4 + tl;
    float v[NCLS];
    float m = -1e30f;
    #pragma unroll
    for (int c = 0; c < NCLS; ++c) { v[c] = lds[tl][b][c] + bd[c]; m = fmaxf(m, v[c]); }
    float sum = 0.f;
    #pragma unroll
    for (int c = 0; c < NCLS; ++c) { float e = __expf(v[c] - m); v[c] = e; sum += e; }
    float inv = 1.f / sum;
    float* op = out + ((size_t)b * T_SEQ + tt) * NCLS;
    #pragma unroll
    for (int c = 0; c < NCLS; ++c) op[c] = v[c] * inv;
  }
}

// ---------------- launch ----------------
extern "C" void kernel_launch(void* const* d_in, const int* in_sizes, int n_in,
                              void* d_out, int out_size, void* d_ws, size_t ws_size,
                              hipStream_t stream) {
  const float* x  = (const float*)d_in[0];
  const float* Wf = (const float*)d_in[1];
  const float* Uf = (const float*)d_in[2];
  const float* bf = (const float*)d_in[3];
  const float* Wb = (const float*)d_in[4];
  const float* Ub = (const float*)d_in[5];
  const float* bb = (const float*)d_in[6];
  const float* Wd = (const float*)d_in[7];
  const float* bd = (const float*)d_in[8];
  float* out = (float*)d_out;

  char* ws = (char*)d_ws;
  ushort* xT    = (ushort*)(ws + 0);          // 16,777,216 B
  ushort* UWT   = (ushort*)(ws + 16777216);   //  4,718,592 B
  ushort* WdTp  = (ushort*)(ws + 21495808);   //    131,072 B
  ushort* h_buf = (ushort*)(ws + 21626880);   // 67,108,864 B
  int*    flags = (int*)   (ws + 88735744);   //    131,072 B  (total ~88.9 MB)

  hipMemsetAsync(flags, 0, 2 * T_SEQ * NG * sizeof(int), stream);
  hipLaunchKernelGGL(prep_xT,       dim3(4096), dim3(256), 0, stream, x, xT);
  hipLaunchKernelGGL(prep_UWT,      dim3(1152), dim3(256), 0, stream, Uf, Wf, Ub, Wb, UWT);
  hipLaunchKernelGGL(prep_WdT,      dim3(256),  dim3(256), 0, stream, Wd, WdTp);
  hipLaunchKernelGGL(gru_rec,       dim3(32),   dim3(192), 0, stream, xT, UWT, bf, bb, h_buf, flags);
  hipLaunchKernelGGL(dense_softmax, dim3(256),  dim3(256), 0, stream, h_buf, WdTp, bd, out);
}

// Round 3
// 7425.315 us; speedup vs baseline: 1.4908x; 1.4908x over previous
//
#include <hip/hip_runtime.h>
#include <hip/hip_bf16.h>

#define F_IN  256
#define UNITS 512
#define T_SEQ 1024
#define B_SZ  32
#define NCLS  50
#define NG    16    // workgroups per direction
#define NWAVE 6     // waves per workgroup
#define NTAGS 96    // NG * NWAVE tags per (dir, step)
#define SCOPE __HIP_MEMORY_SCOPE_AGENT

typedef short s16x8 __attribute__((ext_vector_type(8)));
typedef float f32x16 __attribute__((ext_vector_type(16)));

__device__ __forceinline__ ushort f2bf(float f) {
  union { float f; unsigned u; } v; v.f = f;
  unsigned r = v.u + 0x7fffu + ((v.u >> 16) & 1u);   // round-to-nearest-even
  return (ushort)(r >> 16);
}

// ---------------- prep kernels ----------------

// x [32][1024][256] f32  ->  xT [1024][32][256] bf16
__global__ void prep_xT(const float* __restrict__ x, ushort* __restrict__ xT) {
  int idx = blockIdx.x * 256 + threadIdx.x;      // chunk of 8 over [32][1024][32]
  int b = idx >> 15;
  int r = idx & 32767;
  int t = r >> 5;
  int c = r & 31;
  const float4* s4 = (const float4*)(x + ((size_t)b * T_SEQ + t) * F_IN + c * 8);
  float4 f0 = s4[0], f1 = s4[1];
  s16x8 o;
  o[0] = (short)f2bf(f0.x); o[1] = (short)f2bf(f0.y);
  o[2] = (short)f2bf(f0.z); o[3] = (short)f2bf(f0.w);
  o[4] = (short)f2bf(f1.x); o[5] = (short)f2bf(f1.y);
  o[6] = (short)f2bf(f1.z); o[7] = (short)f2bf(f1.w);
  *(s16x8*)(xT + ((size_t)t * B_SZ + b) * F_IN + c * 8) = o;
}

// UWT[d][n][k] bf16, n in [0,1536), k in [0,768): k<512 -> U_d[k][n], k>=512 -> W_d[k-512][n]
__global__ void prep_UWT(const float* __restrict__ Uf, const float* __restrict__ Wf,
                         const float* __restrict__ Ub, const float* __restrict__ Wb,
                         ushort* __restrict__ UWT) {
  int idx = blockIdx.x * 256 + threadIdx.x;      // chunk of 8 over [2][1536][96]
  int d = idx / 147456;
  int r = idx % 147456;
  int n = r / 96;
  int ck = r % 96;
  const float* U = d ? Ub : Uf;
  const float* W = d ? Wb : Wf;
  s16x8 o;
  #pragma unroll
  for (int i = 0; i < 8; ++i) {
    int k = ck * 8 + i;
    float v = (k < UNITS) ? U[(size_t)k * 1536 + n] : W[(size_t)(k - UNITS) * 1536 + n];
    o[i] = (short)f2bf(v);
  }
  *(s16x8*)(UWT + ((size_t)d * 1536 + n) * 768 + ck * 8) = o;
}

// WdT [64][1024] bf16 (rows 50..63 zero) from Wd [1024][50]
__global__ void prep_WdT(const float* __restrict__ Wd, ushort* __restrict__ WdT) {
  int idx = blockIdx.x * 256 + threadIdx.x;      // 65536
  int n = idx >> 10, k = idx & 1023;
  float v = (n < NCLS) ? Wd[(size_t)k * NCLS + n] : 0.f;
  WdT[idx] = f2bf(v);
}

// ---------------- persistent bidirectional GRU recurrence ----------------
// 32 WGs (16/dir) x 384 threads (6 waves). Wave wv: gate = wv>>1 (z/r/h),
// K-half kh = wv&1 (K[0:384) pure-h, K[384:768) = h[384:512)+x[0:256)).
// 24 B-fragments per wave (96 VGPRs) -> no spill.
// Publish protocol (per wave, per step): payload write-through stores ->
// s_waitcnt vmcnt(0) (acked at coherence point) -> one tag word = s+1.
// Consumers poll the 96 tag words (bypass atomic loads), then read payload
// with PLAIN cached loads (first touch of each line is post-tag; kernel
// boundary invalidates L2 -- proven by prep->gru plain-load path in R2).
// Cross-step LDS WAR hazard is covered transitively: a wave writes its next
// slot only after its poll passed; the poll requires every wave's tag; a
// wave's tag is stored only after its gate-math LDS reads completed.
__global__ __launch_bounds__(384, 2) void gru_rec(
    const ushort* __restrict__ xT,      // [1024][32][256] bf16
    const ushort* __restrict__ UWT,     // [2][1536][768] bf16
    const float* __restrict__ bias_f,   // [2][1536] f32
    const float* __restrict__ bias_b,
    ushort* __restrict__ h_out,         // [2][1024][32][512] bf16
    unsigned* __restrict__ tags)        // [2][1024][96]
{
  const int g  = blockIdx.x;
  const int d  = g >> 4;
  const int gg = g & 15;
  const int tid  = threadIdx.x;
  const int wv   = tid >> 6;
  const int lane = tid & 63;
  const int col  = lane & 31;
  const int half = lane >> 5;
  const int gate = wv >> 1;
  const int kh   = wv & 1;

  __shared__ float slot[2][32][128];  // [kh][row][ z(0:32) r(32:64) rh(64:96) xh(96:128) ]

  // --- B-fragment preload: 24 chunks of K=16 (96 VGPRs) ---
  s16x8 bfrag[24];
  {
    const ushort* bp = UWT + ((size_t)d * 1536 + gate * UNITS + gg * 32 + col) * 768
                       + kh * 384 + half * 8;
    #pragma unroll
    for (int c = 0; c < 24; ++c) bfrag[c] = *(const s16x8*)(bp + c * 16);
  }

  // --- per-thread gate biases and persistent h state (3 elems/thread) ---
  const float* bias = d ? bias_b : bias_f;
  float bz[3], br[3], bih[3], brh[3], hprev[3];
  #pragma unroll
  for (int i = 0; i < 3; ++i) {
    int e = tid + 384 * i;
    int j = gg * 32 + (e & 31);
    bz[i] = br[i] = bih[i] = brh[i] = 0.f;
    hprev[i] = 0.f;
    if (e < 1024) {
      bz[i]  = bias[j]        + bias[1536 + j];
      br[i]  = bias[512 + j]  + bias[1536 + 512 + j];
      bih[i] = bias[1024 + j];
      brh[i] = bias[1536 + 1024 + j];
    }
  }

  for (int s = 0; s < T_SEQ; ++s) {
    const int t_in = d ? (T_SEQ - 1 - s) : s;
    f32x16 acc_a, acc_b;
    #pragma unroll
    for (int i = 0; i < 16; ++i) { acc_a[i] = 0.f; acc_b[i] = 0.f; }

    // input projection (kh==1 waves own K[512:768) = x): independent of the poll
    if (kh) {
      const ushort* xp = xT + ((size_t)t_in * B_SZ + col) * F_IN + half * 8;
      #pragma unroll
      for (int grp = 0; grp < 2; ++grp) {
        s16x8 a[8];
        #pragma unroll
        for (int i = 0; i < 8; ++i) a[i] = *(const s16x8*)(xp + (grp * 8 + i) * 16);
        #pragma unroll
        for (int i = 0; i < 8; ++i)
          acc_b = __builtin_amdgcn_mfma_f32_32x32x16_bf16(a[i], bfrag[8 + grp * 8 + i], acc_b, 0, 0, 0);
      }
    }

    if (s > 0) {
      // poll all 96 producer-wave tags of step s-1 (bypass loads)
      const unsigned expv = (unsigned)s;
      const unsigned* tg = tags + (size_t)(d * T_SEQ + (s - 1)) * NTAGS;
      bool ok;
      do {
        unsigned v0 = __hip_atomic_load(tg + lane, __ATOMIC_RELAXED, SCOPE);
        unsigned v1 = (lane < 32)
            ? __hip_atomic_load(tg + 64 + lane, __ATOMIC_RELAXED, SCOPE) : expv;
        ok = (v0 == expv) && (v1 == expv);
      } while (!__all(ok));
      __builtin_amdgcn_sched_barrier(0);
      asm volatile("" ::: "memory");

      const int t_prev = d ? (T_SEQ - s) : (s - 1);
      const ushort* ap = h_out + ((size_t)(d * T_SEQ + t_prev) * B_SZ + col) * UNITS
                         + kh * 384 + half * 8;
      if (kh) {               // h[384:512): 1 group of 8 fragments
        s16x8 a[8];
        #pragma unroll
        for (int i = 0; i < 8; ++i) a[i] = *(const s16x8*)(ap + i * 16);
        #pragma unroll
        for (int i = 0; i < 8; ++i)
          acc_a = __builtin_amdgcn_mfma_f32_32x32x16_bf16(a[i], bfrag[i], acc_a, 0, 0, 0);
      } else {                // h[0:384): 3 groups of 8
        #pragma unroll
        for (int grp = 0; grp < 3; ++grp) {
          s16x8 a[8];
          #pragma unroll
          for (int i = 0; i < 8; ++i) a[i] = *(const s16x8*)(ap + (grp * 8 + i) * 16);
          #pragma unroll
          for (int i = 0; i < 8; ++i)
            acc_a = __builtin_amdgcn_mfma_f32_32x32x16_bf16(a[i], bfrag[grp * 8 + i], acc_a, 0, 0, 0);
        }
      }
    }

    // C/D layout: col = lane&31, row = (reg&3) + 8*(reg>>2) + 4*(lane>>5)
    #pragma unroll
    for (int i = 0; i < 16; ++i) {
      int brow = (i & 3) + 8 * (i >> 2) + 4 * half;
      if (gate < 2) {
        slot[kh][brow][gate * 32 + col] = acc_a[i] + acc_b[i];
      } else {
        slot[kh][brow][64 + col] = acc_a[i];          // recurrent h-gate partial
        if (kh) slot[1][brow][96 + col] = acc_b[i];   // input h-gate part
      }
    }
    __syncthreads();

    // gate math + publish h_new (write-through stores), then per-wave tag
    #pragma unroll
    for (int i = 0; i < 3; ++i) {
      int e = tid + 384 * i;
      if (e < 1024) {
        int b = e >> 5, j = e & 31;
        float rz = slot[0][b][j]      + slot[1][b][j]      + bz[i];
        float rr = slot[0][b][32 + j] + slot[1][b][32 + j] + br[i];
        float rh = slot[0][b][64 + j] + slot[1][b][64 + j] + brh[i];
        float xh = slot[1][b][96 + j] + bih[i];
        rz = fminf(fmaxf(rz, -30.f), 30.f);
        rr = fminf(fmaxf(rr, -30.f), 30.f);
        float z  = 1.f / (1.f + __expf(-rz));
        float rg = 1.f / (1.f + __expf(-rr));
        float ti = xh + rg * rh;
        ti = fminf(fmaxf(ti, -15.f), 15.f);
        float ex = __expf(2.f * ti);
        float hh = (ex - 1.f) / (ex + 1.f);
        float hn = z * hprev[i] + (1.f - z) * hh;
        hprev[i] = hn;
        __hip_atomic_store(
            h_out + ((size_t)(d * T_SEQ + t_in) * B_SZ + b) * UNITS + gg * 32 + j,
            (ushort)f2bf(hn), __ATOMIC_RELAXED, SCOPE);
      }
    }
    // all this wave's payload stores acked at the coherence point, then tag
    asm volatile("s_waitcnt vmcnt(0)" ::: "memory");
    if (lane == 0)
      __hip_atomic_store(tags + (size_t)(d * T_SEQ + s) * NTAGS + gg * NWAVE + wv,
                         (unsigned)(s + 1), __ATOMIC_RELAXED, SCOPE);
  }
}

// ---------------- dense + softmax ----------------
__global__ __launch_bounds__(256) void dense_softmax(
    const ushort* __restrict__ h_out,   // [2][1024][32][512] bf16
    const ushort* __restrict__ WdT,     // [64][1024] bf16
    const float* __restrict__ bd,       // [50]
    float* __restrict__ out)            // [32][1024][50] f32
{
  const int tid  = threadIdx.x;
  const int w    = tid >> 6, lane = tid & 63;
  const int col  = lane & 31, half = lane >> 5;
  const int t = blockIdx.x * 4 + w;

  __shared__ float lds[4][32][66];

  f32x16 acc0, acc1;
  #pragma unroll
  for (int i = 0; i < 16; ++i) { acc0[i] = 0.f; acc1[i] = 0.f; }

  const ushort* af  = h_out + ((size_t)t * B_SZ + col) * UNITS + half * 8;
  const ushort* ab  = h_out + ((size_t)(T_SEQ + t) * B_SZ + col) * UNITS + half * 8;
  const ushort* bp0 = WdT + (size_t)col * 1024 + half * 8;
  const ushort* bp1 = WdT + (size_t)(col + 32) * 1024 + half * 8;

  #pragma unroll 4
  for (int ks = 0; ks < 64; ++ks) {
    s16x8 a  = (ks < 32) ? *(const s16x8*)(af + ks * 16)
                         : *(const s16x8*)(ab + (ks - 32) * 16);
    s16x8 b0 = *(const s16x8*)(bp0 + ks * 16);
    s16x8 b1 = *(const s16x8*)(bp1 + ks * 16);
    acc0 = __builtin_amdgcn_mfma_f32_32x32x16_bf16(a, b0, acc0, 0, 0, 0);
    acc1 = __builtin_amdgcn_mfma_f32_32x32x16_bf16(a, b1, acc1, 0, 0, 0);
  }

  #pragma unroll
  for (int i = 0; i < 16; ++i) {
    int b = (i & 3) + 8 * (i >> 2) + 4 * half;
    lds[w][b][col]      = acc0[i];
    lds[w][b][32 + col] = acc1[i];
  }
  __syncthreads();

  if (tid < 128) {
    int tl = tid >> 5, b = tid & 31;
    int tt = blockIdx.x * 4 + tl;
    float v[NCLS];
    float m = -1e30f;
    #pragma unroll
    for (int c = 0; c < NCLS; ++c) { v[c] = lds[tl][b][c] + bd[c]; m = fmaxf(m, v[c]); }
    float sum = 0.f;
    #pragma unroll
    for (int c = 0; c < NCLS; ++c) { float e = __expf(v[c] - m); v[c] = e; sum += e; }
    float inv = 1.f / sum;
    float* op = out + ((size_t)b * T_SEQ + tt) * NCLS;
    #pragma unroll
    for (int c = 0; c < NCLS; ++c) op[c] = v[c] * inv;
  }
}

// ---------------- launch ----------------
extern "C" void kernel_launch(void* const* d_in, const int* in_sizes, int n_in,
                              void* d_out, int out_size, void* d_ws, size_t ws_size,
                              hipStream_t stream) {
  const float* x  = (const float*)d_in[0];
  const float* Wf = (const float*)d_in[1];
  const float* Uf = (const float*)d_in[2];
  const float* bf = (const float*)d_in[3];
  const float* Wb = (const float*)d_in[4];
  const float* Ub = (const float*)d_in[5];
  const float* bb = (const float*)d_in[6];
  const float* Wd = (const float*)d_in[7];
  const float* bd = (const float*)d_in[8];
  float* out = (float*)d_out;

  char* ws = (char*)d_ws;
  ushort*   xT    = (ushort*)  (ws + 0);          // 16,777,216 B
  ushort*   UWT   = (ushort*)  (ws + 16777216);   //  4,718,592 B
  ushort*   WdTp  = (ushort*)  (ws + 21495808);   //    131,072 B
  ushort*   h_buf = (ushort*)  (ws + 21626880);   // 67,108,864 B
  unsigned* tags  = (unsigned*)(ws + 88735744);   //    786,432 B  (total ~89.5 MB)

  hipMemsetAsync(tags, 0, 2 * T_SEQ * NTAGS * sizeof(unsigned), stream);
  hipLaunchKernelGGL(prep_xT,       dim3(4096), dim3(256), 0, stream, x, xT);
  hipLaunchKernelGGL(prep_UWT,      dim3(1152), dim3(256), 0, stream, Uf, Wf, Ub, Wb, UWT);
  hipLaunchKernelGGL(prep_WdT,      dim3(256),  dim3(256), 0, stream, Wd, WdTp);
  hipLaunchKernelGGL(gru_rec,       dim3(32),   dim3(384), 0, stream, xT, UWT, bf, bb, h_buf, tags);
  hipLaunchKernelGGL(dense_softmax, dim3(256),  dim3(256), 0, stream, h_buf, WdTp, bd, out);
}

// Round 5
// 7077.499 us; speedup vs baseline: 1.5641x; 1.0491x over previous
//
#include <hip/hip_runtime.h>
#include <hip/hip_bf16.h>

#define F_IN  256
#define UNITS 512
#define T_SEQ 1024
#define B_SZ  32
#define NCLS  50
#define NG    16    // workgroups per direction
#define NWAVE 6     // waves per workgroup
#define SCOPE __HIP_MEMORY_SCOPE_AGENT

typedef short s16x8 __attribute__((ext_vector_type(8)));
typedef float f32x16 __attribute__((ext_vector_type(16)));

__device__ __forceinline__ ushort f2bf(float f) {
  union { float f; unsigned u; } v; v.f = f;
  unsigned r = v.u + 0x7fffu + ((v.u >> 16) & 1u);   // round-to-nearest-even
  return (ushort)(r >> 16);
}

// ---------------- prep kernels ----------------

// x [32][1024][256] f32  ->  xT [1024][32][256] bf16
__global__ void prep_xT(const float* __restrict__ x, ushort* __restrict__ xT) {
  int idx = blockIdx.x * 256 + threadIdx.x;      // chunk of 8 over [32][1024][32]
  int b = idx >> 15;
  int r = idx & 32767;
  int t = r >> 5;
  int c = r & 31;
  const float4* s4 = (const float4*)(x + ((size_t)b * T_SEQ + t) * F_IN + c * 8);
  float4 f0 = s4[0], f1 = s4[1];
  s16x8 o;
  o[0] = (short)f2bf(f0.x); o[1] = (short)f2bf(f0.y);
  o[2] = (short)f2bf(f0.z); o[3] = (short)f2bf(f0.w);
  o[4] = (short)f2bf(f1.x); o[5] = (short)f2bf(f1.y);
  o[6] = (short)f2bf(f1.z); o[7] = (short)f2bf(f1.w);
  *(s16x8*)(xT + ((size_t)t * B_SZ + b) * F_IN + c * 8) = o;
}

// UWT[d][n][k] bf16, n in [0,1536), k in [0,768): k<512 -> U_d[k][n], k>=512 -> W_d[k-512][n]
__global__ void prep_UWT(const float* __restrict__ Uf, const float* __restrict__ Wf,
                         const float* __restrict__ Ub, const float* __restrict__ Wb,
                         ushort* __restrict__ UWT) {
  int idx = blockIdx.x * 256 + threadIdx.x;      // chunk of 8 over [2][1536][96]
  int d = idx / 147456;
  int r = idx % 147456;
  int n = r / 96;
  int ck = r % 96;
  const float* U = d ? Ub : Uf;
  const float* W = d ? Wb : Wf;
  s16x8 o;
  #pragma unroll
  for (int i = 0; i < 8; ++i) {
    int k = ck * 8 + i;
    float v = (k < UNITS) ? U[(size_t)k * 1536 + n] : W[(size_t)(k - UNITS) * 1536 + n];
    o[i] = (short)f2bf(v);
  }
  *(s16x8*)(UWT + ((size_t)d * 1536 + n) * 768 + ck * 8) = o;
}

// WdT [64][1024] bf16 (rows 50..63 zero) from Wd [1024][50]
__global__ void prep_WdT(const float* __restrict__ Wd, ushort* __restrict__ WdT) {
  int idx = blockIdx.x * 256 + threadIdx.x;      // 65536
  int n = idx >> 10, k = idx & 1023;
  float v = (n < NCLS) ? Wd[(size_t)k * NCLS + n] : 0.f;
  WdT[idx] = f2bf(v);
}

// ---------------- persistent bidirectional GRU recurrence ----------------
// 32 WGs (16/dir) x 384 threads (6 waves). Wave wv: gate = wv>>1 (z/r/h),
// K-half kh = wv&1 (K[0:384) pure-h, K[384:768) = h[384:512)+x[0:256)).
// Sync protocol (v2, congestion-reduced):
//   producer: gate math -> agent-scope bf16 stores (write-through to L3
//             coherence point) -> __syncthreads (drains vmcnt in every wave)
//             -> ONE tag word per WG, monotone value s+1.
//   consumer: wave 0 ONLY polls the 16 WG-tags (>= s, one relaxed agent load
//             per lane per iter, s_sleep backoff); __syncthreads releases the
//             other 5 waves; then plain cached payload loads -> MFMA.
// Plain consumer loads are safe: every dispatch starts with L1/L2 invalidated,
// and within a dispatch each h line is written (bypass) once before any read.
// Cross-step LDS WAR hazard: a WG writes slot[] at step s+1 only after the
// poll saw its OWN tag >= s+1, which is stored only after the barrier that
// follows its gate-math LDS reads at step s.
__global__ __launch_bounds__(384, 2) void gru_rec(
    const ushort* __restrict__ xT,      // [1024][32][256] bf16
    const ushort* __restrict__ UWT,     // [2][1536][768] bf16
    const float* __restrict__ bias_f,   // [2][1536] f32
    const float* __restrict__ bias_b,
    ushort* __restrict__ h_out,         // [2][1024][32][512] bf16
    unsigned* __restrict__ tags)        // [2][16] monotone step counters
{
  const int g  = blockIdx.x;
  const int d  = g >> 4;
  const int gg = g & 15;
  const int tid  = threadIdx.x;
  const int wv   = tid >> 6;
  const int lane = tid & 63;
  const int col  = lane & 31;
  const int half = lane >> 5;
  const int gate = wv >> 1;
  const int kh   = wv & 1;

  __shared__ float slot[2][32][128];  // [kh][row][ z(0:32) r(32:64) rh(64:96) xh(96:128) ]

  // --- B-fragment preload: 24 chunks of K=16 (96 VGPRs) ---
  s16x8 bfrag[24];
  {
    const ushort* bp = UWT + ((size_t)d * 1536 + gate * UNITS + gg * 32 + col) * 768
                       + kh * 384 + half * 8;
    #pragma unroll
    for (int c = 0; c < 24; ++c) bfrag[c] = *(const s16x8*)(bp + c * 16);
  }

  // --- per-thread gate biases and persistent h state (3 elems/thread) ---
  const float* bias = d ? bias_b : bias_f;
  float bz[3], br[3], bih[3], brh[3], hprev[3];
  #pragma unroll
  for (int i = 0; i < 3; ++i) {
    int e = tid + 384 * i;
    int j = gg * 32 + (e & 31);
    bz[i] = br[i] = bih[i] = brh[i] = 0.f;
    hprev[i] = 0.f;
    if (e < 1024) {
      bz[i]  = bias[j]        + bias[1536 + j];
      br[i]  = bias[512 + j]  + bias[1536 + 512 + j];
      bih[i] = bias[1024 + j];
      brh[i] = bias[1536 + 1024 + j];
    }
  }

  for (int s = 0; s < T_SEQ; ++s) {
    const int t_in = d ? (T_SEQ - 1 - s) : s;
    f32x16 acc_a, acc_b;
    #pragma unroll
    for (int i = 0; i < 16; ++i) { acc_a[i] = 0.f; acc_b[i] = 0.f; }

    // input projection (kh==1 waves own K[512:768) = x). Wave 0 (kh=0) has no
    // x-work: it proceeds straight to the poll.
    if (kh) {
      const ushort* xp = xT + ((size_t)t_in * B_SZ + col) * F_IN + half * 8;
      #pragma unroll
      for (int grp = 0; grp < 2; ++grp) {
        s16x8 a[8];
        #pragma unroll
        for (int i = 0; i < 8; ++i) a[i] = *(const s16x8*)(xp + (grp * 8 + i) * 16);
        #pragma unroll
        for (int i = 0; i < 8; ++i)
          acc_b = __builtin_amdgcn_mfma_f32_32x32x16_bf16(a[i], bfrag[8 + grp * 8 + i], acc_b, 0, 0, 0);
      }
    }

    if (s > 0) {
      if (wv == 0) {
        const unsigned expv = (unsigned)s;
        const unsigned* tg = tags + d * NG;
        bool done;
        do {
          unsigned v = (lane < NG)
              ? __hip_atomic_load(tg + lane, __ATOMIC_RELAXED, SCOPE) : expv;
          done = __all(v >= expv);
          if (!done) __builtin_amdgcn_s_sleep(1);
        } while (!done);
      }
      __syncthreads();   // B1: release all waves; full fence for payload loads

      const int t_prev = d ? (T_SEQ - s) : (s - 1);
      const ushort* ap = h_out + ((size_t)(d * T_SEQ + t_prev) * B_SZ + col) * UNITS
                         + kh * 384 + half * 8;
      if (kh) {               // h[384:512): 8 fragments
        s16x8 a[8];
        #pragma unroll
        for (int i = 0; i < 8; ++i) a[i] = *(const s16x8*)(ap + i * 16);
        #pragma unroll
        for (int i = 0; i < 8; ++i)
          acc_a = __builtin_amdgcn_mfma_f32_32x32x16_bf16(a[i], bfrag[i], acc_a, 0, 0, 0);
      } else {                // h[0:384): 24 fragments, 2 batches of 12
        #pragma unroll
        for (int grp = 0; grp < 2; ++grp) {
          s16x8 a[12];
          #pragma unroll
          for (int i = 0; i < 12; ++i) a[i] = *(const s16x8*)(ap + (grp * 12 + i) * 16);
          #pragma unroll
          for (int i = 0; i < 12; ++i)
            acc_a = __builtin_amdgcn_mfma_f32_32x32x16_bf16(a[i], bfrag[grp * 12 + i], acc_a, 0, 0, 0);
        }
      }
    }

    // C/D layout: col = lane&31, row = (reg&3) + 8*(reg>>2) + 4*(lane>>5)
    #pragma unroll
    for (int i = 0; i < 16; ++i) {
      int brow = (i & 3) + 8 * (i >> 2) + 4 * half;
      if (gate < 2) {
        slot[kh][brow][gate * 32 + col] = acc_a[i] + acc_b[i];
      } else {
        slot[kh][brow][64 + col] = acc_a[i];          // recurrent h-gate partial
        if (kh) slot[1][brow][96 + col] = acc_b[i];   // input h-gate part
      }
    }
    __syncthreads();   // B2: slot complete

    // gate math + publish h_new (agent-scope write-through stores)
    #pragma unroll
    for (int i = 0; i < 3; ++i) {
      int e = tid + 384 * i;
      if (e < 1024) {
        int b = e >> 5, j = e & 31;
        float rz = slot[0][b][j]      + slot[1][b][j]      + bz[i];
        float rr = slot[0][b][32 + j] + slot[1][b][32 + j] + br[i];
        float rh = slot[0][b][64 + j] + slot[1][b][64 + j] + brh[i];
        float xh = slot[1][b][96 + j] + bih[i];
        rz = fminf(fmaxf(rz, -30.f), 30.f);
        rr = fminf(fmaxf(rr, -30.f), 30.f);
        float z  = 1.f / (1.f + __expf(-rz));
        float rg = 1.f / (1.f + __expf(-rr));
        float ti = xh + rg * rh;
        ti = fminf(fmaxf(ti, -15.f), 15.f);
        float ex = __expf(2.f * ti);
        float hh = (ex - 1.f) / (ex + 1.f);
        float hn = z * hprev[i] + (1.f - z) * hh;
        hprev[i] = hn;
        __hip_atomic_store(
            h_out + ((size_t)(d * T_SEQ + t_in) * B_SZ + b) * UNITS + gg * 32 + j,
            (ushort)f2bf(hn), __ATOMIC_RELAXED, SCOPE);
      }
    }
    // B3: __syncthreads drains vmcnt(0) in every wave -> all 6 waves' payload
    // stores are at the coherence point; then ONE tag store per WG.
    __syncthreads();
    if (tid == 0)
      __hip_atomic_store(tags + d * NG + gg, (unsigned)(s + 1),
                         __ATOMIC_RELAXED, SCOPE);
  }
}

// ---------------- dense + softmax ----------------
__global__ __launch_bounds__(256) void dense_softmax(
    const ushort* __restrict__ h_out,   // [2][1024][32][512] bf16
    const ushort* __restrict__ WdT,     // [64][1024] bf16
    const float* __restrict__ bd,       // [50]
    float* __restrict__ out)            // [32][1024][50] f32
{
  const int tid  = threadIdx.x;
  const int w    = tid >> 6, lane = tid & 63;
  const int col  = lane & 31, half = lane >> 5;
  const int t = blockIdx.x * 4 + w;

  __shared__ float lds[4][32][66];

  f32x16 acc0, acc1;
  #pragma unroll
  for (int i = 0; i < 16; ++i) { acc0[i] = 0.f; acc1[i] = 0.f; }

  const ushort* af  = h_out + ((size_t)t * B_SZ + col) * UNITS + half * 8;
  const ushort* ab  = h_out + ((size_t)(T_SEQ + t) * B_SZ + col) * UNITS + half * 8;
  const ushort* bp0 = WdT + (size_t)col * 1024 + half * 8;
  const ushort* bp1 = WdT + (size_t)(col + 32) * 1024 + half * 8;

  #pragma unroll 4
  for (int ks = 0; ks < 64; ++ks) {
    s16x8 a  = (ks < 32) ? *(const s16x8*)(af + ks * 16)
                         : *(const s16x8*)(ab + (ks - 32) * 16);
    s16x8 b0 = *(const s16x8*)(bp0 + ks * 16);
    s16x8 b1 = *(const s16x8*)(bp1 + ks * 16);
    acc0 = __builtin_amdgcn_mfma_f32_32x32x16_bf16(a, b0, acc0, 0, 0, 0);
    acc1 = __builtin_amdgcn_mfma_f32_32x32x16_bf16(a, b1, acc1, 0, 0, 0);
  }

  #pragma unroll
  for (int i = 0; i < 16; ++i) {
    int b = (i & 3) + 8 * (i >> 2) + 4 * half;
    lds[w][b][col]      = acc0[i];
    lds[w][b][32 + col] = acc1[i];
  }
  __syncthreads();

  if (tid < 128) {
    int tl = tid >> 5, b = tid & 31;
    int tt = blockIdx.x * 4 + tl;
    float v[NCLS];
    float m = -1e30f;
    #pragma unroll
    for (int c = 0; c < NCLS; ++c) { v[c] = lds[tl][b][c] + bd[c]; m = fmaxf(m, v[c]); }
    float sum = 0.f;
    #pragma unroll
    for (int c = 0; c < NCLS; ++c) { float e = __expf(v[c] - m); v[c] = e; sum += e; }
    float inv = 1.f / sum;
    float* op = out + ((size_t)b * T_SEQ + tt) * NCLS;
    #pragma unroll
    for (int c = 0; c < NCLS; ++c) op[c] = v[c] * inv;
  }
}

// ---------------- launch ----------------
extern "C" void kernel_launch(void* const* d_in, const int* in_sizes, int n_in,
                              void* d_out, int out_size, void* d_ws, size_t ws_size,
                              hipStream_t stream) {
  const float* x  = (const float*)d_in[0];
  const float* Wf = (const float*)d_in[1];
  const float* Uf = (const float*)d_in[2];
  const float* bf = (const float*)d_in[3];
  const float* Wb = (const float*)d_in[4];
  const float* Ub = (const float*)d_in[5];
  const float* bb = (const float*)d_in[6];
  const float* Wd = (const float*)d_in[7];
  const float* bd = (const float*)d_in[8];
  float* out = (float*)d_out;

  char* ws = (char*)d_ws;
  ushort*   xT    = (ushort*)  (ws + 0);          // 16,777,216 B
  ushort*   UWT   = (ushort*)  (ws + 16777216);   //  4,718,592 B
  ushort*   WdTp  = (ushort*)  (ws + 21495808);   //    131,072 B
  ushort*   h_buf = (ushort*)  (ws + 21626880);   // 67,108,864 B
  unsigned* tags  = (unsigned*)(ws + 88735744);   //        128 B  (total ~88.7 MB)

  hipMemsetAsync(tags, 0, 2 * NG * sizeof(unsigned), stream);
  hipLaunchKernelGGL(prep_xT,       dim3(4096), dim3(256), 0, stream, x, xT);
  hipLaunchKernelGGL(prep_UWT,      dim3(1152), dim3(256), 0, stream, Uf, Wf, Ub, Wb, UWT);
  hipLaunchKernelGGL(prep_WdT,      dim3(256),  dim3(256), 0, stream, Wd, WdTp);
  hipLaunchKernelGGL(gru_rec,       dim3(32),   dim3(384), 0, stream, xT, UWT, bf, bb, h_buf, tags);
  hipLaunchKernelGGL(dense_softmax, dim3(256),  dim3(256), 0, stream, h_buf, WdTp, bd, out);
}